// Round 1
// baseline (961.016 us; speedup 1.0000x reference)
//
#include <hip/hip_runtime.h>
#include <math.h>

typedef __attribute__((ext_vector_type(8))) short short8_t;
typedef __attribute__((ext_vector_type(4))) float f32x4;

__device__ __forceinline__ short f2bf(float f) {
  unsigned u = __builtin_bit_cast(unsigned, f);
  u = (u + 0x7fffu + ((u >> 16) & 1u)) >> 16;   // round-to-nearest-even
  return (short)u;
}
__device__ __forceinline__ float sigmoid_f(float x) { return 1.f / (1.f + expf(-x)); }
__device__ __forceinline__ float silu_f(float x)    { return x / (1.f + expf(-x)); }

// ---------------------------------------------------------------------------
// Router: one wave per token. logits[t,e] = hs[t,:]·rw[e,:] (fp32).
// scores[e,t] = (e==argmax) ? sigmoid(logit) : 0   (sigmoid(-inf)==0 exactly)
// scale[e] (e<8) = scores[0][token e]  (the reference's rows-scale quirk)
// ---------------------------------------------------------------------------
__global__ __launch_bounds__(256) void router_kernel(
    const float* __restrict__ hs, const float* __restrict__ rw,
    float* __restrict__ scores, float* __restrict__ scale, int T, int H) {
  const int wave = threadIdx.x >> 6, lane = threadIdx.x & 63;
  const int t = blockIdx.x * 4 + wave;
  if (t >= T) return;
  float acc[8] = {0.f,0.f,0.f,0.f,0.f,0.f,0.f,0.f};
  for (int h = lane * 4; h < H; h += 256) {
    const float4 x = *(const float4*)(hs + (size_t)t * H + h);
#pragma unroll
    for (int e = 0; e < 8; ++e) {
      const float4 wv = *(const float4*)(rw + (size_t)e * H + h);
      acc[e] += x.x*wv.x + x.y*wv.y + x.z*wv.z + x.w*wv.w;
    }
  }
#pragma unroll
  for (int e = 0; e < 8; ++e)
#pragma unroll
    for (int off = 32; off > 0; off >>= 1)
      acc[e] += __shfl_xor(acc[e], off, 64);
  if (lane == 0) {
    int amax = 0; float best = acc[0];
#pragma unroll
    for (int e = 1; e < 8; ++e) if (acc[e] > best) { best = acc[e]; amax = e; }
#pragma unroll
    for (int e = 0; e < 8; ++e)
      scores[(size_t)e * T + t] = (e == amax) ? sigmoid_f(acc[e]) : 0.f;
    if (t < 8) scale[t] = (amax == 0) ? sigmoid_f(acc[0]) : 0.f;
  }
}

// ---------------------------------------------------------------------------
// Expert gate/up GEMV: act[e,i] = silu(s*hs[e]·gw[e,i]) * (s*hs[e]·uw[e,i])
// Blocks for scale==0 experts exit immediately (exact-zero contribution).
// ---------------------------------------------------------------------------
__global__ __launch_bounds__(256) void expert_gateup_kernel(
    const float* __restrict__ hs, const float* __restrict__ gw,
    const float* __restrict__ uw, const float* __restrict__ scale,
    float* __restrict__ act, int H, int I) {
  const int e = blockIdx.y;
  const float s = scale[e];
  if (s == 0.f) return;
  const int wave = threadIdx.x >> 6, lane = threadIdx.x & 63;
  const float* hrow = hs + (size_t)e * H;
#pragma unroll
  for (int j = 0; j < 4; ++j) {
    const int i = blockIdx.x * 16 + j * 4 + wave;
    const float* grow = gw + ((size_t)e * I + i) * H;
    const float* urow = uw + ((size_t)e * I + i) * H;
    float pg = 0.f, pu = 0.f;
    for (int h = lane * 4; h < H; h += 256) {
      const float4 x  = *(const float4*)(hrow + h);
      const float4 g4 = *(const float4*)(grow + h);
      const float4 u4 = *(const float4*)(urow + h);
      pg += x.x*g4.x + x.y*g4.y + x.z*g4.z + x.w*g4.w;
      pu += x.x*u4.x + x.y*u4.y + x.z*u4.z + x.w*u4.w;
    }
#pragma unroll
    for (int off = 32; off > 0; off >>= 1) {
      pg += __shfl_xor(pg, off, 64);
      pu += __shfl_xor(pu, off, 64);
    }
    if (lane == 0) {
      const float g = s * pg, u = s * pu;
      act[(size_t)e * I + i] = silu_f(g) * u;
    }
  }
}

// ---------------------------------------------------------------------------
// Expert down GEMV + cross-expert sum: bias[h] += act[e,:]·dw[e,h,:]
// ---------------------------------------------------------------------------
__global__ __launch_bounds__(256) void expert_down_kernel(
    const float* __restrict__ act, const float* __restrict__ dw,
    const float* __restrict__ scale, float* __restrict__ bias, int H, int I) {
  const int e = blockIdx.y;
  if (scale[e] == 0.f) return;
  const int wave = threadIdx.x >> 6, lane = threadIdx.x & 63;
  const int h = blockIdx.x * 4 + wave;
  const float* drow = dw + ((size_t)e * H + h) * I;
  const float* arow = act + (size_t)e * I;
  float p = 0.f;
  for (int i = lane * 4; i < I; i += 256) {
    const float4 a = *(const float4*)(arow + i);
    const float4 d = *(const float4*)(drow + i);
    p += a.x*d.x + a.y*d.y + a.z*d.z + a.w*d.w;
  }
#pragma unroll
  for (int off = 32; off > 0; off >>= 1) p += __shfl_xor(p, off, 64);
  if (lane == 0) atomicAdd(bias + h, p);
}

// ---------------------------------------------------------------------------
// GEMM staging helpers: 128x32 tile into bf16 LDS ([row][k], stride 32)
// ---------------------------------------------------------------------------
__device__ __forceinline__ void stage_f32_tile(short* __restrict__ dst,
                                               const float* __restrict__ src,
                                               int ldk, int tid) {
  const int r = tid >> 3;          // 0..31
  const int c = (tid & 7) << 2;    // 0,4,..,28
#pragma unroll
  for (int it = 0; it < 4; ++it) {
    const float4 v = *(const float4*)(src + (size_t)(r + it * 32) * ldk + c);
    short4 hv;
    hv.x = f2bf(v.x); hv.y = f2bf(v.y); hv.z = f2bf(v.z); hv.w = f2bf(v.w);
    *(short4*)(dst + (r + it * 32) * 32 + c) = hv;
  }
}
__device__ __forceinline__ void stage_bf16_tile(short* __restrict__ dst,
                                                const short* __restrict__ src,
                                                int ldk, int tid) {
  const int r = tid >> 2;          // 0..63
  const int c = (tid & 3) << 3;    // 0,8,16,24
#pragma unroll
  for (int it = 0; it < 2; ++it) {
    const int4 v = *(const int4*)(src + (size_t)(r + it * 64) * ldk + c);
    *(int4*)(dst + (r + it * 64) * 32 + c) = v;
  }
}

// ---------------------------------------------------------------------------
// Fused gate+up GEMM: Act[t,i] = bf16( silu(X·Wg^T) * (X·Wu^T) )
// 128x128 tile / block, 4 waves each 64x64 (4x4 of 16x16x32 bf16 MFMA), BK=32.
// A/B frag: row/col = lane&15, k = (lane>>4)*8 + j. C/D: col=lane&15,
// row=(lane>>4)*4+r  (m89/m91-verified mappings).
// ---------------------------------------------------------------------------
__global__ __launch_bounds__(256) void gemm_gateup_kernel(
    const float* __restrict__ X, const float* __restrict__ Wg,
    const float* __restrict__ Wu, short* __restrict__ Act,
    int M, int N, int K) {
  __shared__ short As[128 * 32];
  __shared__ short Bgs[128 * 32];
  __shared__ short Bus[128 * 32];
  const int tid = threadIdx.x;
  const int lane = tid & 63, wave = tid >> 6;
  const int wm = wave & 1, wn = wave >> 1;
  const int m0 = blockIdx.x * 128, n0 = blockIdx.y * 128;
  const f32x4 vzero = {0.f, 0.f, 0.f, 0.f};
  f32x4 accg[4][4], accu[4][4];
#pragma unroll
  for (int mi = 0; mi < 4; ++mi)
#pragma unroll
    for (int ni = 0; ni < 4; ++ni) { accg[mi][ni] = vzero; accu[mi][ni] = vzero; }
  const float* Ap  = X  + (size_t)m0 * K;
  const float* Bgp = Wg + (size_t)n0 * K;
  const float* Bup = Wu + (size_t)n0 * K;
  const int row = lane & 15, q = lane >> 4;
  for (int k0 = 0; k0 < K; k0 += 32) {
    stage_f32_tile(As,  Ap  + k0, K, tid);
    stage_f32_tile(Bgs, Bgp + k0, K, tid);
    stage_f32_tile(Bus, Bup + k0, K, tid);
    __syncthreads();
    short8_t a[4], bg[4], bu[4];
#pragma unroll
    for (int i = 0; i < 4; ++i) {
      a[i]  = *(const short8_t*)(As  + (wm * 64 + i * 16 + row) * 32 + q * 8);
      bg[i] = *(const short8_t*)(Bgs + (wn * 64 + i * 16 + row) * 32 + q * 8);
      bu[i] = *(const short8_t*)(Bus + (wn * 64 + i * 16 + row) * 32 + q * 8);
    }
#pragma unroll
    for (int mi = 0; mi < 4; ++mi)
#pragma unroll
      for (int ni = 0; ni < 4; ++ni) {
        accg[mi][ni] = __builtin_amdgcn_mfma_f32_16x16x32_bf16(a[mi], bg[ni], accg[mi][ni], 0, 0, 0);
        accu[mi][ni] = __builtin_amdgcn_mfma_f32_16x16x32_bf16(a[mi], bu[ni], accu[mi][ni], 0, 0, 0);
      }
    __syncthreads();
  }
  const int col = lane & 15, rb = (lane >> 4) * 4;
#pragma unroll
  for (int mi = 0; mi < 4; ++mi)
#pragma unroll
    for (int ni = 0; ni < 4; ++ni)
#pragma unroll
      for (int r = 0; r < 4; ++r) {
        const int gm = m0 + wm * 64 + mi * 16 + rb + r;
        const int gn = n0 + wn * 64 + ni * 16 + col;
        const float g = accg[mi][ni][r];
        const float u = accu[mi][ni][r];
        Act[(size_t)gm * N + gn] = f2bf(silu_f(g) * u);
      }
}

// ---------------------------------------------------------------------------
// Down GEMM: Out[t,h] = Act(bf16)·Wd[h,:]^T + bias[h]   (fp32 out)
// ---------------------------------------------------------------------------
__global__ __launch_bounds__(256) void gemm_down_kernel(
    const short* __restrict__ Aact, const float* __restrict__ Wd,
    const float* __restrict__ bias, float* __restrict__ Out,
    int M, int N, int K) {
  __shared__ short As[128 * 32];
  __shared__ short Bs[128 * 32];
  const int tid = threadIdx.x;
  const int lane = tid & 63, wave = tid >> 6;
  const int wm = wave & 1, wn = wave >> 1;
  const int m0 = blockIdx.x * 128, n0 = blockIdx.y * 128;
  const f32x4 vzero = {0.f, 0.f, 0.f, 0.f};
  f32x4 acc[4][4];
#pragma unroll
  for (int mi = 0; mi < 4; ++mi)
#pragma unroll
    for (int ni = 0; ni < 4; ++ni) acc[mi][ni] = vzero;
  const short* Ap = Aact + (size_t)m0 * K;
  const float* Bp = Wd + (size_t)n0 * K;
  const int row = lane & 15, q = lane >> 4;
  for (int k0 = 0; k0 < K; k0 += 32) {
    stage_bf16_tile(As, Ap + k0, K, tid);
    stage_f32_tile(Bs, Bp + k0, K, tid);
    __syncthreads();
    short8_t a[4], b[4];
#pragma unroll
    for (int i = 0; i < 4; ++i) {
      a[i] = *(const short8_t*)(As + (wm * 64 + i * 16 + row) * 32 + q * 8);
      b[i] = *(const short8_t*)(Bs + (wn * 64 + i * 16 + row) * 32 + q * 8);
    }
#pragma unroll
    for (int mi = 0; mi < 4; ++mi)
#pragma unroll
      for (int ni = 0; ni < 4; ++ni)
        acc[mi][ni] = __builtin_amdgcn_mfma_f32_16x16x32_bf16(a[mi], b[ni], acc[mi][ni], 0, 0, 0);
    __syncthreads();
  }
  const int col = lane & 15, rb = (lane >> 4) * 4;
#pragma unroll
  for (int mi = 0; mi < 4; ++mi)
#pragma unroll
    for (int ni = 0; ni < 4; ++ni)
#pragma unroll
      for (int r = 0; r < 4; ++r) {
        const int gm = m0 + wm * 64 + mi * 16 + rb + r;
        const int gn = n0 + wn * 64 + ni * 16 + col;
        Out[(size_t)gm * N + gn] = acc[mi][ni][r] + bias[gn];
      }
}

// ---------------------------------------------------------------------------
extern "C" void kernel_launch(void* const* d_in, const int* in_sizes, int n_in,
                              void* d_out, int out_size, void* d_ws, size_t ws_size,
                              hipStream_t stream) {
  const float* hs  = (const float*)d_in[0];
  const float* rw  = (const float*)d_in[1];
  const float* sgw = (const float*)d_in[2];
  const float* suw = (const float*)d_in[3];
  const float* sdw = (const float*)d_in[4];
  const float* egw = (const float*)d_in[5];
  const float* euw = (const float*)d_in[6];
  const float* edw = (const float*)d_in[7];

  const int E = in_sizes[5] / in_sizes[2];   // (E*I*H)/(I*H)
  const int H = in_sizes[1] / E;
  const int I = in_sizes[2] / H;
  const int T = in_sizes[0] / H;

  float* out    = (float*)d_out;
  float* scores = out + (size_t)T * H;

  // workspace carve (all rewritten every call; ws is poisoned between calls)
  char* w = (char*)d_ws;
  float* scale = (float*)w;  w += 256;
  float* bias  = (float*)w;  w += ((size_t)H * 4 + 255) & ~(size_t)255;
  float* act   = (float*)w;  w += ((size_t)E * I * 4 + 255) & ~(size_t)255;
  short* Aact  = (short*)w;  // T*I bf16 (~16 MB)

  router_kernel<<<dim3(T / 4), 256, 0, stream>>>(hs, rw, scores, scale, T, H);
  hipMemsetAsync(bias, 0, (size_t)H * sizeof(float), stream);
  expert_gateup_kernel<<<dim3(I / 16, E), 256, 0, stream>>>(hs, egw, euw, scale, act, H, I);
  expert_down_kernel<<<dim3(H / 4, E), 256, 0, stream>>>(act, edw, scale, bias, H, I);
  gemm_gateup_kernel<<<dim3(T / 128, I / 128), 256, 0, stream>>>(hs, sgw, suw, Aact, T, I, H);
  gemm_down_kernel<<<dim3(T / 128, H / 128), 256, 0, stream>>>(Aact, sdw, bias, out, T, H, I);
}

// Round 2
// 871.407 us; speedup vs baseline: 1.1028x; 1.1028x over previous
//
#include <hip/hip_runtime.h>
#include <math.h>

typedef __attribute__((ext_vector_type(8))) short short8_t;
typedef __attribute__((ext_vector_type(4))) float f32x4;
typedef unsigned int u32;

__device__ __forceinline__ short f2bf(float f) {
  unsigned u = __builtin_bit_cast(unsigned, f);
  u = (u + 0x7fffu + ((u >> 16) & 1u)) >> 16;   // round-to-nearest-even
  return (short)u;
}
__device__ __forceinline__ float sigmoid_f(float x) { return 1.f / (1.f + expf(-x)); }
__device__ __forceinline__ float silu_f(float x)    { return x / (1.f + expf(-x)); }

// async 16B global->LDS (m97 path; LDS dest = wave-uniform base + lane*16)
__device__ __forceinline__ void gload_lds16(const void* g, void* l) {
  __builtin_amdgcn_global_load_lds(
      (const __attribute__((address_space(1))) u32*)g,
      (__attribute__((address_space(3))) u32*)l, 16, 0, 0);
}

// ---------------------------------------------------------------------------
// f32 -> bf16 bulk convert (8 elem/thread)
// ---------------------------------------------------------------------------
__global__ __launch_bounds__(256) void cvt_bf16_kernel(
    const float* __restrict__ src, short* __restrict__ dst, int n) {
  const int i = (blockIdx.x * 256 + threadIdx.x) * 8;
  if (i >= n) return;
  const float4 v0 = *(const float4*)(src + i);
  const float4 v1 = *(const float4*)(src + i + 4);
  short8_t o;
  o[0] = f2bf(v0.x); o[1] = f2bf(v0.y); o[2] = f2bf(v0.z); o[3] = f2bf(v0.w);
  o[4] = f2bf(v1.x); o[5] = f2bf(v1.y); o[6] = f2bf(v1.z); o[7] = f2bf(v1.w);
  *(short8_t*)(dst + i) = o;
}

// ---------------------------------------------------------------------------
// Router: one wave per token (fp32 exact). scores[e,t] = sigmoid at argmax
// else 0; scale[e] (e<8) = scores[0][token e] (reference's rows quirk).
// ---------------------------------------------------------------------------
__global__ __launch_bounds__(256) void router_kernel(
    const float* __restrict__ hs, const float* __restrict__ rw,
    float* __restrict__ scores, float* __restrict__ scale, int T, int H) {
  const int wave = threadIdx.x >> 6, lane = threadIdx.x & 63;
  const int t = blockIdx.x * 4 + wave;
  if (t >= T) return;
  float acc[8] = {0.f,0.f,0.f,0.f,0.f,0.f,0.f,0.f};
  for (int h = lane * 4; h < H; h += 256) {
    const float4 x = *(const float4*)(hs + (size_t)t * H + h);
#pragma unroll
    for (int e = 0; e < 8; ++e) {
      const float4 wv = *(const float4*)(rw + (size_t)e * H + h);
      acc[e] += x.x*wv.x + x.y*wv.y + x.z*wv.z + x.w*wv.w;
    }
  }
#pragma unroll
  for (int e = 0; e < 8; ++e)
#pragma unroll
    for (int off = 32; off > 0; off >>= 1)
      acc[e] += __shfl_xor(acc[e], off, 64);
  if (lane == 0) {
    int amax = 0; float best = acc[0];
#pragma unroll
    for (int e = 1; e < 8; ++e) if (acc[e] > best) { best = acc[e]; amax = e; }
#pragma unroll
    for (int e = 0; e < 8; ++e)
      scores[(size_t)e * T + t] = (e == amax) ? sigmoid_f(acc[e]) : 0.f;
    if (t < 8) scale[t] = (amax == 0) ? sigmoid_f(acc[0]) : 0.f;
  }
}

// ---------------------------------------------------------------------------
// Expert gate/up GEMV (fp32): act[e,i] = silu(s*hs[e]·gw) * (s*hs[e]·uw)
// scale==0 blocks exit (exact-zero contribution).
// ---------------------------------------------------------------------------
__global__ __launch_bounds__(256) void expert_gateup_kernel(
    const float* __restrict__ hs, const float* __restrict__ gw,
    const float* __restrict__ uw, const float* __restrict__ scale,
    float* __restrict__ act, int H, int I) {
  const int e = blockIdx.y;
  const float s = scale[e];
  if (s == 0.f) return;
  const int wave = threadIdx.x >> 6, lane = threadIdx.x & 63;
  const float* hrow = hs + (size_t)e * H;
#pragma unroll
  for (int j = 0; j < 4; ++j) {
    const int i = blockIdx.x * 16 + j * 4 + wave;
    const float* grow = gw + ((size_t)e * I + i) * H;
    const float* urow = uw + ((size_t)e * I + i) * H;
    float pg = 0.f, pu = 0.f;
    for (int h = lane * 4; h < H; h += 256) {
      const float4 x  = *(const float4*)(hrow + h);
      const float4 g4 = *(const float4*)(grow + h);
      const float4 u4 = *(const float4*)(urow + h);
      pg += x.x*g4.x + x.y*g4.y + x.z*g4.z + x.w*g4.w;
      pu += x.x*u4.x + x.y*u4.y + x.z*u4.z + x.w*u4.w;
    }
#pragma unroll
    for (int off = 32; off > 0; off >>= 1) {
      pg += __shfl_xor(pg, off, 64);
      pu += __shfl_xor(pu, off, 64);
    }
    if (lane == 0) act[(size_t)e * I + i] = silu_f(s * pg) * (s * pu);
  }
}

// ---------------------------------------------------------------------------
// Expert down GEMV + cross-expert sum: bias[h] += act[e,:]·dw[e,h,:]
// ---------------------------------------------------------------------------
__global__ __launch_bounds__(256) void expert_down_kernel(
    const float* __restrict__ act, const float* __restrict__ dw,
    const float* __restrict__ scale, float* __restrict__ bias, int H, int I) {
  const int e = blockIdx.y;
  if (scale[e] == 0.f) return;
  const int wave = threadIdx.x >> 6, lane = threadIdx.x & 63;
  const int h = blockIdx.x * 4 + wave;
  const float* drow = dw + ((size_t)e * H + h) * I;
  const float* arow = act + (size_t)e * I;
  float p = 0.f;
  for (int i = lane * 4; i < I; i += 256) {
    const float4 a = *(const float4*)(arow + i);
    const float4 d = *(const float4*)(drow + i);
    p += a.x*d.x + a.y*d.y + a.z*d.z + a.w*d.w;
  }
#pragma unroll
  for (int off = 32; off > 0; off >>= 1) p += __shfl_xor(p, off, 64);
  if (lane == 0) atomicAdd(bias + h, p);
}

// ---------------------------------------------------------------------------
// m97-style bf16 GEMMs: 128x128 tile, BK=32, global_load_lds width-16,
// XOR-swizzled LDS chunks (chunk c at row holds k-chunk c^((row>>1)&3)),
// which reduces ds_read_b128 8-way conflicts to free 2-way.
// LDS tile layout: 128 rows x 32 shorts (64B/row); staged as tid*16B,
// issue*4096B -> row = issue*64 + tid/4, chunk = tid&3 (DMA-contiguous).
// MFMA 16x16x32 bf16; A/B frag row/col=lane&15, k=(lane>>4)*8+j;
// C/D col=lane&15, row=(lane>>4)*4+r  (m89/m91-verified).
// ---------------------------------------------------------------------------

// fused gate+up: Act[t,i] = bf16( silu(X·Wg^T) * (X·Wu^T) ), all bf16 in
__global__ __launch_bounds__(256) void gemm_gateup_kernel(
    const short* __restrict__ X, const short* __restrict__ Wg,
    const short* __restrict__ Wu, short* __restrict__ Act,
    int M, int N, int K) {
  __shared__ short As[128 * 32];
  __shared__ short Bgs[128 * 32];
  __shared__ short Bus[128 * 32];
  const int tid = threadIdx.x, lane = tid & 63, wave = tid >> 6;
  const int wm = wave & 1, wn = wave >> 1;
  const int m0 = blockIdx.x * 128, n0 = blockIdx.y * 128;

  // staging: per-thread global offset (swizzled chunk), per-thread LDS slot
  const int srow = tid >> 2;
  const int schunk = (tid & 3) ^ ((tid >> 3) & 3);
  const size_t a0 = (size_t)(m0 + srow) * K + schunk * 8;
  const size_t a1 = (size_t)(m0 + 64 + srow) * K + schunk * 8;
  const size_t b0 = (size_t)(n0 + srow) * K + schunk * 8;
  const size_t b1 = (size_t)(n0 + 64 + srow) * K + schunk * 8;
  short* lA0 = As + tid * 8;          short* lA1 = As + 2048 + tid * 8;
  short* lG0 = Bgs + tid * 8;         short* lG1 = Bgs + 2048 + tid * 8;
  short* lU0 = Bus + tid * 8;         short* lU1 = Bus + 2048 + tid * 8;

  const f32x4 vz = {0.f,0.f,0.f,0.f};
  f32x4 accg[4][4], accu[4][4];
#pragma unroll
  for (int mi = 0; mi < 4; ++mi)
#pragma unroll
    for (int ni = 0; ni < 4; ++ni) { accg[mi][ni] = vz; accu[mi][ni] = vz; }

  const int row16 = lane & 15, q = lane >> 4;
  const int koff = (q ^ ((row16 >> 1) & 3)) * 8;   // swizzled read chunk

  for (int k0 = 0; k0 < K; k0 += 32) {
    gload_lds16(X + a0 + k0, lA0);  gload_lds16(X + a1 + k0, lA1);
    gload_lds16(Wg + b0 + k0, lG0); gload_lds16(Wg + b1 + k0, lG1);
    gload_lds16(Wu + b0 + k0, lU0); gload_lds16(Wu + b1 + k0, lU1);
    __syncthreads();
    short8_t a[4], bg[4], bu[4];
#pragma unroll
    for (int i = 0; i < 4; ++i) {
      a[i]  = *(const short8_t*)(As  + (wm * 64 + i * 16 + row16) * 32 + koff);
      bg[i] = *(const short8_t*)(Bgs + (wn * 64 + i * 16 + row16) * 32 + koff);
      bu[i] = *(const short8_t*)(Bus + (wn * 64 + i * 16 + row16) * 32 + koff);
    }
#pragma unroll
    for (int mi = 0; mi < 4; ++mi)
#pragma unroll
      for (int ni = 0; ni < 4; ++ni) {
        accg[mi][ni] = __builtin_amdgcn_mfma_f32_16x16x32_bf16(a[mi], bg[ni], accg[mi][ni], 0, 0, 0);
        accu[mi][ni] = __builtin_amdgcn_mfma_f32_16x16x32_bf16(a[mi], bu[ni], accu[mi][ni], 0, 0, 0);
      }
    __syncthreads();
  }
  const int col = lane & 15, rb = (lane >> 4) * 4;
#pragma unroll
  for (int mi = 0; mi < 4; ++mi)
#pragma unroll
    for (int ni = 0; ni < 4; ++ni)
#pragma unroll
      for (int r = 0; r < 4; ++r) {
        const int gm = m0 + wm * 64 + mi * 16 + rb + r;
        const int gn = n0 + wn * 64 + ni * 16 + col;
        Act[(size_t)gm * N + gn] = f2bf(silu_f(accg[mi][ni][r]) * accu[mi][ni][r]);
      }
}

// down: Out[t,h] = Act·Wd^T + bias[h]  (bf16 in, fp32 out)
__global__ __launch_bounds__(256) void gemm_down_kernel(
    const short* __restrict__ Aact, const short* __restrict__ Wd,
    const float* __restrict__ bias, float* __restrict__ Out,
    int M, int N, int K) {
  __shared__ short As[128 * 32];
  __shared__ short Bs[128 * 32];
  const int tid = threadIdx.x, lane = tid & 63, wave = tid >> 6;
  const int wm = wave & 1, wn = wave >> 1;
  const int m0 = blockIdx.x * 128, n0 = blockIdx.y * 128;
  const int srow = tid >> 2;
  const int schunk = (tid & 3) ^ ((tid >> 3) & 3);
  const size_t a0 = (size_t)(m0 + srow) * K + schunk * 8;
  const size_t a1 = (size_t)(m0 + 64 + srow) * K + schunk * 8;
  const size_t b0 = (size_t)(n0 + srow) * K + schunk * 8;
  const size_t b1 = (size_t)(n0 + 64 + srow) * K + schunk * 8;
  short* lA0 = As + tid * 8;  short* lA1 = As + 2048 + tid * 8;
  short* lB0 = Bs + tid * 8;  short* lB1 = Bs + 2048 + tid * 8;

  const f32x4 vz = {0.f,0.f,0.f,0.f};
  f32x4 acc[4][4];
#pragma unroll
  for (int mi = 0; mi < 4; ++mi)
#pragma unroll
    for (int ni = 0; ni < 4; ++ni) acc[mi][ni] = vz;

  const int row16 = lane & 15, q = lane >> 4;
  const int koff = (q ^ ((row16 >> 1) & 3)) * 8;

  for (int k0 = 0; k0 < K; k0 += 32) {
    gload_lds16(Aact + a0 + k0, lA0); gload_lds16(Aact + a1 + k0, lA1);
    gload_lds16(Wd + b0 + k0, lB0);   gload_lds16(Wd + b1 + k0, lB1);
    __syncthreads();
    short8_t a[4], b[4];
#pragma unroll
    for (int i = 0; i < 4; ++i) {
      a[i] = *(const short8_t*)(As + (wm * 64 + i * 16 + row16) * 32 + koff);
      b[i] = *(const short8_t*)(Bs + (wn * 64 + i * 16 + row16) * 32 + koff);
    }
#pragma unroll
    for (int mi = 0; mi < 4; ++mi)
#pragma unroll
      for (int ni = 0; ni < 4; ++ni)
        acc[mi][ni] = __builtin_amdgcn_mfma_f32_16x16x32_bf16(a[mi], b[ni], acc[mi][ni], 0, 0, 0);
    __syncthreads();
  }
  const int col = lane & 15, rb = (lane >> 4) * 4;
#pragma unroll
  for (int mi = 0; mi < 4; ++mi)
#pragma unroll
    for (int ni = 0; ni < 4; ++ni)
#pragma unroll
      for (int r = 0; r < 4; ++r) {
        const int gm = m0 + wm * 64 + mi * 16 + rb + r;
        const int gn = n0 + wn * 64 + ni * 16 + col;
        Out[(size_t)gm * N + gn] = acc[mi][ni][r] + bias[gn];
      }
}

// ---------------------------------------------------------------------------
extern "C" void kernel_launch(void* const* d_in, const int* in_sizes, int n_in,
                              void* d_out, int out_size, void* d_ws, size_t ws_size,
                              hipStream_t stream) {
  const float* hs  = (const float*)d_in[0];
  const float* rw  = (const float*)d_in[1];
  const float* sgw = (const float*)d_in[2];
  const float* suw = (const float*)d_in[3];
  const float* sdw = (const float*)d_in[4];
  const float* egw = (const float*)d_in[5];
  const float* euw = (const float*)d_in[6];
  const float* edw = (const float*)d_in[7];

  const int E = in_sizes[5] / in_sizes[2];
  const int H = in_sizes[1] / E;
  const int I = in_sizes[2] / H;
  const int T = in_sizes[0] / H;

  float* out    = (float*)d_out;
  float* scores = out + (size_t)T * H;

  // workspace carve (rewritten every call)
  char* w = (char*)d_ws;
  float* scale = (float*)w;  w += 256;
  float* bias  = (float*)w;  w += ((size_t)H * 4 + 255) & ~(size_t)255;
  float* act   = (float*)w;  w += ((size_t)E * I * 4 + 255) & ~(size_t)255;
  short* hsb   = (short*)w;  w += ((size_t)T * H * 2 + 255) & ~(size_t)255;
  short* gb    = (short*)w;  w += ((size_t)I * H * 2 + 255) & ~(size_t)255;
  short* ub    = (short*)w;  w += ((size_t)I * H * 2 + 255) & ~(size_t)255;
  short* db    = (short*)w;  w += ((size_t)H * I * 2 + 255) & ~(size_t)255;
  short* Aact  = (short*)w;  // T*I bf16

  router_kernel<<<dim3(T / 4), 256, 0, stream>>>(hs, rw, scores, scale, T, H);
  hipMemsetAsync(bias, 0, (size_t)H * sizeof(float), stream);

  const int nTH = T * H, nIH = I * H;
  cvt_bf16_kernel<<<dim3(nTH / 2048), 256, 0, stream>>>(hs, hsb, nTH);
  cvt_bf16_kernel<<<dim3(nIH / 2048), 256, 0, stream>>>(sgw, gb, nIH);
  cvt_bf16_kernel<<<dim3(nIH / 2048), 256, 0, stream>>>(suw, ub, nIH);
  cvt_bf16_kernel<<<dim3(nIH / 2048), 256, 0, stream>>>(sdw, db, nIH);

  expert_gateup_kernel<<<dim3(I / 16, E), 256, 0, stream>>>(hs, egw, euw, scale, act, H, I);
  expert_down_kernel<<<dim3(H / 4, E), 256, 0, stream>>>(act, edw, scale, bias, H, I);

  gemm_gateup_kernel<<<dim3(T / 128, I / 128), 256, 0, stream>>>(hsb, gb, ub, Aact, T, I, H);
  gemm_down_kernel<<<dim3(T / 128, H / 128), 256, 0, stream>>>(Aact, db, bias, out, T, H, I);
}